// Round 7
// baseline (1768.084 us; speedup 1.0000x reference)
//
#include <hip/hip_runtime.h>
#include <cstdint>
#include <cstddef>

// nODE: 50 Euler steps of  x <- x*(1+dt*gamma) + dt*tanh(x @ W^T + b)
// Round 12 = R11 with the build_wl/kernel lane-permutation mismatch FIXED.
// R11's absmax 1.99 was wrong-W: build_wl stored fragments at group index
// l16*4+quad (R7's register-path order) while the DMA staging sourced at
// group index lane=quad*16+l16. build_wl now stores lane-indexed fragments;
// kernel unchanged.
// Theory under test (from R10 post-mortem): WRITE_SIZE anomaly (296MB vs
// 64MB output) = register-spill scratch whose L2 churn evicts the shared
// 512KB W set -> recurring W fetch insensitive to demand (R7), prefetch
// depth (R9), placement (R10). Moving B from VGPR ring to LDS DMA staging
// (per-wave-private, double-buffered) frees the spill AND makes every B
// request a contiguous 1KB wave transaction.

#define D_DIM 512
#define NSTEPS 50
#define A_STRIDE 520   // elems; row = 1040 B (16B-aligned)

typedef __bf16 bf16x8 __attribute__((ext_vector_type(8)));
typedef float f32x4 __attribute__((ext_vector_type(4)));
typedef unsigned short ushort8_t __attribute__((ext_vector_type(8)));

__device__ __forceinline__ unsigned short f_to_bf16_bits(float f) {
    union { float f; unsigned int i; } c;
    c.f = f;
    unsigned int u = c.i;
    unsigned int r = (u + 0x7fffu + ((u >> 16) & 1u)) >> 16;  // RNE
    return (unsigned short)r;
}

// Wl frag layout (lane-indexed; matches kernel's DMA source):
//   f = ((w*16 + kb)*4 + t)*64 + lane, elems [f*8+j] =
//     bf16( W[w*64 + sigma(t*16 + (lane&15))][kb*32 + (lane>>4)*8 + j] ),
//   sigma(i) = 4*(i&15) + (i>>4)   (same output-col permutation as R5).
// Lane l's 16B fragment sits at byte l*16 of each 1KB (kb,t) block.
__global__ __launch_bounds__(256) void build_wl(
    const float* __restrict__ W, unsigned short* __restrict__ Wl) {
    int f    = blockIdx.x * 256 + threadIdx.x;   // 0..32767, one frag each
    int lane = f & 63;
    int t    = (f >> 6) & 3;
    int kb   = (f >> 8) & 15;
    int w    = f >> 12;
    int l16  = lane & 15;
    int quad = lane >> 4;
    int i    = t * 16 + l16;
    int srow = w * 64 + 4 * (i & 15) + (i >> 4);
    int k0   = kb * 32 + quad * 8;
    float4 a = *(const float4*)&W[(size_t)srow * D_DIM + k0];
    float4 b = *(const float4*)&W[(size_t)srow * D_DIM + k0 + 4];
    ushort8_t o;
    o[0] = f_to_bf16_bits(a.x); o[1] = f_to_bf16_bits(a.y);
    o[2] = f_to_bf16_bits(a.z); o[3] = f_to_bf16_bits(a.w);
    o[4] = f_to_bf16_bits(b.x); o[5] = f_to_bf16_bits(b.y);
    o[6] = f_to_bf16_bits(b.z); o[7] = f_to_bf16_bits(b.w);
    *(ushort8_t*)&Wl[(size_t)f * 8] = o;
}

__global__ __launch_bounds__(512, 2) void node_persist(
    const float* __restrict__ X,              // fp32 [32768][512]
    const unsigned short* __restrict__ Wl,    // bf16 lane-indexed frag W
    const float* __restrict__ bias,           // [512]
    const float* __restrict__ gamma,          // [512]
    float* __restrict__ Fout)                 // fp32 [32768][512]
{
    __shared__ unsigned short ldsA[64 * A_STRIDE];     // 66,560 B state-hi
    __shared__ unsigned short ldsB[2][8][4][64 * 8];   // 65,536 B B-slices

    const int tid  = threadIdx.x;
    const int lane = tid & 63;
    const int w    = tid >> 6;        // wave 0..7 -> col strip [w*64, w*64+64)
    const int l16  = lane & 15;
    const int quad = lane >> 4;
    const int bm   = blockIdx.x;      // 0..511, rows [bm*64, bm*64+64)
    const float dt = 1.0f / 50.0f;

    // Lane's 4 TRUE output cols (thanks to sigma row-perm of W).
    const int ctrue0 = w * 64 + 4 * l16;

    // Per-lane B global base: frag (kb,t) 16B at + kb*2048 + t*512 elems.
    const unsigned short* bpw = Wl + (size_t)w * 32768 + (size_t)lane * 8;

    // Column constants.
    float bc_[4], g1_[4];
    {
        float4 b4 = *(const float4*)&bias[ctrue0];
        float4 g4 = *(const float4*)&gamma[ctrue0];
        bc_[0] = b4.x; bc_[1] = b4.y; bc_[2] = b4.z; bc_[3] = b4.w;
        g1_[0] = 1.0f + dt * g4.x; g1_[1] = 1.0f + dt * g4.y;
        g1_[2] = 1.0f + dt * g4.z; g1_[3] = 1.0f + dt * g4.w;
    }

    // Initial state: s[tm][tn][r] = state of (row r0+tm*16+r, col ctrue0+tn).
    const int r0 = quad * 4;
    float s[4][4][4];
#pragma unroll
    for (int tm = 0; tm < 4; ++tm)
#pragma unroll
        for (int r = 0; r < 4; ++r) {
            float4 v = *(const float4*)
                &X[(size_t)(bm * 64 + r0 + tm * 16 + r) * D_DIM + ctrue0];
            s[tm][0][r] = v.x; s[tm][1][r] = v.y;
            s[tm][2][r] = v.z; s[tm][3][r] = v.w;
        }

    // Initial state-hi into ldsA (b64 writes).
#pragma unroll
    for (int tm = 0; tm < 4; ++tm)
#pragma unroll
        for (int r = 0; r < 4; ++r) {
            ushort4 h;
            h.x = f_to_bf16_bits(s[tm][0][r]);
            h.y = f_to_bf16_bits(s[tm][1][r]);
            h.z = f_to_bf16_bits(s[tm][2][r]);
            h.w = f_to_bf16_bits(s[tm][3][r]);
            *(ushort4*)&ldsA[(r0 + tm * 16 + r) * A_STRIDE + ctrue0] = h;
        }

    // Stage B slice (kb_): 4 async 16B/lane DMA loads into this wave's
    // private ldsB buffer (kb_&1). Global src is per-lane (lane l reads byte
    // l*16 of a contiguous 1KB block); LDS dst is wave-uniform base +
    // lane*16 (DMA semantics) -- source and destination orders match.
#define STAGE(kb_) do {                                                      \
    const int b_ = (kb_) & 1, s_ = (kb_) & 15;                               \
    _Pragma("unroll")                                                        \
    for (int t_ = 0; t_ < 4; ++t_)                                           \
        __builtin_amdgcn_global_load_lds(                                    \
            (const __attribute__((address_space(1))) unsigned int*)          \
                (bpw + (size_t)s_ * 2048 + t_ * 512),                        \
            (__attribute__((address_space(3))) unsigned int*)                \
                &ldsB[b_][w][t_][0],                                         \
            16, 0, 0);                                                       \
} while (0)

    STAGE(0);          // prime slice 0 (lands by the barrier's vmcnt drain)

    __syncthreads();   // ldsA fully written (also drains vmcnt)

    for (int step = 0; step < NSTEPS; ++step) {
        f32x4 acc[4][4];
#pragma unroll
        for (int tm = 0; tm < 4; ++tm)
#pragma unroll
            for (int tn = 0; tn < 4; ++tn) {
                f32x4 b4 = {bc_[tn], bc_[tn], bc_[tn], bc_[tn]};
                acc[tm][tn] = b4;   // bias folded into acc init
            }

#pragma unroll
        for (int kb = 0; kb < 16; ++kb) {
            STAGE(kb + 1);   // next slice (kb=15 -> next step's slice 0)
            // Slice kb's 4 DMAs were issued one iteration ago; the 4 just
            // issued are newer. Wait until only those 4 remain outstanding.
            asm volatile("s_waitcnt vmcnt(4)" ::: "memory");
            __builtin_amdgcn_sched_barrier(0);
            const int b = kb & 1;
            bf16x8 af[4], bf[4];
#pragma unroll
            for (int t = 0; t < 4; ++t) {
                af[t] = *reinterpret_cast<const bf16x8*>(
                    &ldsA[(t * 16 + l16) * A_STRIDE + kb * 32 + quad * 8]);
                bf[t] = *reinterpret_cast<const bf16x8*>(
                    &ldsB[b][w][t][lane * 8]);
            }
#pragma unroll
            for (int tm = 0; tm < 4; ++tm)
#pragma unroll
                for (int tn = 0; tn < 4; ++tn)
                    acc[tm][tn] = __builtin_amdgcn_mfma_f32_16x16x32_bf16(
                        af[tm], bf[tn], acc[tm][tn], 0, 0, 0);
        }

        // Euler update in registers (same formulation -> same numerics).
#pragma unroll
        for (int tm = 0; tm < 4; ++tm)
#pragma unroll
            for (int tn = 0; tn < 4; ++tn)
#pragma unroll
                for (int r = 0; r < 4; ++r) {
                    float y = acc[tm][tn][r];             // includes bias
                    float e = __expf(2.0f * y);
                    float th = 1.0f - 2.0f * __builtin_amdgcn_rcpf(e + 1.0f);
                    s[tm][tn][r] = s[tm][tn][r] * g1_[tn] + dt * th;
                }

        if (step == NSTEPS - 1) break;

        __syncthreads();   // all waves done reading ldsA
#pragma unroll
        for (int tm = 0; tm < 4; ++tm)
#pragma unroll
            for (int r = 0; r < 4; ++r) {
                ushort4 h;
                h.x = f_to_bf16_bits(s[tm][0][r]);
                h.y = f_to_bf16_bits(s[tm][1][r]);
                h.z = f_to_bf16_bits(s[tm][2][r]);
                h.w = f_to_bf16_bits(s[tm][3][r]);
                *(ushort4*)&ldsA[(r0 + tm * 16 + r) * A_STRIDE + ctrue0] = h;
            }
        __syncthreads();   // new state-hi visible (drains in-flight DMA too)
    }

    // Final fp32 store (float4, fully coalesced).
#pragma unroll
    for (int tm = 0; tm < 4; ++tm)
#pragma unroll
        for (int r = 0; r < 4; ++r) {
            float4 v;
            v.x = s[tm][0][r]; v.y = s[tm][1][r];
            v.z = s[tm][2][r]; v.w = s[tm][3][r];
            *(float4*)&Fout[(size_t)(bm * 64 + r0 + tm * 16 + r) * D_DIM + ctrue0] = v;
        }
}

extern "C" void kernel_launch(void* const* d_in, const int* in_sizes, int n_in,
                              void* d_out, int out_size, void* d_ws, size_t ws_size,
                              hipStream_t stream) {
    const float* x  = (const float*)d_in[0];   // [32768][512]
    const float* W  = (const float*)d_in[1];   // [512][512]
    const float* bi = (const float*)d_in[2];   // [512]
    const float* ga = (const float*)d_in[3];   // [512]

    unsigned short* Wl = (unsigned short*)d_ws;   // 512 KB lane-indexed bf16 W

    build_wl<<<128, 256, 0, stream>>>(W, Wl);
    node_persist<<<dim3(512), dim3(512), 0, stream>>>(
        x, Wl, bi, ga, (float*)d_out);
}